// Round 6
// baseline (24044.940 us; speedup 1.0000x reference)
//
#include <hip/hip_runtime.h>
#include <math.h>

#define NPIX 262144
#define CDIM 434
#define KCLS 14
#define MPROTO 10
#define KM 140          // KCLS*MPROTO
#define JPAD 144        // padded col count for GEMM
#define CPAD 448        // padded C (28 chunks of 16)
#define NBLK 1024       // NPIX/256

// ---- workspace float offsets (high-water 7.09 MB) ----
#define OFF_C1    0        // float[140] np col sums iter1
#define OFF_C2    140      // float[140]
#define OFF_C3    280      // float[140]
#define OFF_S32   432      // float[14] global-norm S per class (fp32)
#define OFF_SD    448      // double[14] fp64 accumulator for S
#define OFF_CNTI  480      // int[16] class pixel counts
#define OFF_COFF  496      // int[16] class start offsets in list
#define OFF_CNT   512      // float[140] per-proto accum counts
#define OFF_F     656      // float[140*434 = 60760]
#define OFF_CBITS 61416    // uint[8192] correct bitmask
#define ZERO_N    69608    // zero [0, ZERO_N)
#define OFF_BLKC  69608    // int[1024*14]
#define OFF_BLKO  83944    // int[1024*14]
#define OFF_PT    98280    // float[448*144 = 64512] protos^T padded
#define OFF_PND   162792   // double[140*434] fp64 normalized protos (121520 floats)
#define OFF_STATS 284312   // float4[N]: mu, rstd, linv, 0
#define OFF_LIST  1332888  // int[N] class-sorted stable pixel list
#define OFF_ACCA  1595032  // int[N]

__device__ __forceinline__ float wredsum(float v) {
#pragma unroll
  for (int off = 32; off > 0; off >>= 1) v += __shfl_xor(v, off, 64);
  return v;
}
__device__ __forceinline__ double wredsumd(double v) {
#pragma unroll
  for (int off = 32; off > 0; off >>= 1) v += __shfl_xor(v, off, 64);
  return v;
}

// numpy pairwise sum of 10 contiguous fp32 (n=10 path: 8-unroll + tail)
__device__ __forceinline__ float nprow10(const float L[MPROTO]) {
  float r = ((L[0] + L[1]) + (L[2] + L[3])) + ((L[4] + L[5]) + (L[6] + L[7]));
  r += L[8];
  r += L[9];
  return r;
}

// same structure when value m lives on lane m (lanes 0..9 of a 16-lane group)
__device__ __forceinline__ float nprow_lane(float L) {
  float t = L + __shfl_xor(L, 1, 16);
  t = t + __shfl_xor(t, 2, 16);
  t = t + __shfl_xor(t, 4, 16);          // lanes 0..7: ((0+1)+(2+3))+((4+5)+(6+7))
  float s07 = __shfl(t, 0, 16);
  float L8 = __shfl(L, 8, 16);
  float L9 = __shfl(L, 9, 16);
  return (s07 + L8) + L9;
}

// ---------------- zero small ws region ----------------
__global__ void k_zero(float* ws) {
  int i = blockIdx.x * 256 + threadIdx.x;
  if (i < ZERO_N) ws[i] = 0.f;
}

// ---------------- l2-normalize prototypes (fp64); write pT (fp32) + pnd (fp64) ----
__global__ void k_protonorm(const float* __restrict__ protos, float* __restrict__ pT,
                            double* __restrict__ pnd) {
  int j = blockIdx.x;          // 0..143
  int lane = threadIdx.x;      // 64
  double x[7];
  double ss = 0.0;
#pragma unroll
  for (int i = 0; i < 7; i++) {
    int c = lane + 64 * i;
    double v = (j < KM && c < CDIM) ? (double)protos[(size_t)j * CDIM + c] : 0.0;
    x[i] = v;
    ss += v * v;
  }
  ss = wredsumd(ss);
  double rinv = 1.0 / fmax(sqrt(ss), 1e-12);
#pragma unroll
  for (int i = 0; i < 7; i++) {
    int c = lane + 64 * i;   // covers 0..447 exactly
    double v = x[i] * rinv;
    bool in = (j < KM && c < CDIM);
    if (in) pnd[(size_t)j * CDIM + c] = v;
    pT[(size_t)c * JPAD + j] = in ? (float)v : 0.f;
  }
}

// ---------------- per-row LN + l2 stats (fp32, for GEMM/faccum) ----------------
__global__ __launch_bounds__(256) void k_rowstats(const float* __restrict__ feat,
                                                  const float* __restrict__ g,
                                                  const float* __restrict__ b,
                                                  float4* __restrict__ stats) {
  int wave = threadIdx.x >> 6, lane = threadIdx.x & 63;
  int n = blockIdx.x * 4 + wave;
  const float* row = feat + (size_t)n * CDIM;
  float x[7];
  float s1 = 0.f;
#pragma unroll
  for (int i = 0; i < 7; i++) {
    int c = lane + 64 * i;
    x[i] = (c < CDIM) ? row[c] : 0.f;
    s1 += x[i];
  }
  s1 = wredsum(s1);
  float mu = s1 / (float)CDIM;
  float s2 = 0.f;
#pragma unroll
  for (int i = 0; i < 7; i++) {
    int c = lane + 64 * i;
    float d = (c < CDIM) ? (x[i] - mu) : 0.f;
    s2 += d * d;
  }
  s2 = wredsum(s2);
  float rstd = rsqrtf(s2 / (float)CDIM + 1e-5f);
  float s3 = 0.f;
#pragma unroll
  for (int i = 0; i < 7; i++) {
    int c = lane + 64 * i;
    if (c < CDIM) {
      float y = (x[i] - mu) * rstd * g[c] + b[c];
      s3 += y * y;
    }
  }
  s3 = wredsum(s3);
  float linv = 1.f / fmaxf(sqrtf(s3), 1e-12f);
  if (lane == 0) stats[n] = make_float4(mu, rstd, linv, 0.f);
}

// ---------------- fp64 per-pixel normalized row (one wave per pixel) ----------------
__device__ __forceinline__ void row64(const float* __restrict__ feat, int n,
                                      const float* __restrict__ g, const float* __restrict__ b,
                                      double yc[7]) {
  int lane = threadIdx.x & 63;
  const float* row = feat + (size_t)n * CDIM;
  double x[7];
  double s1 = 0.0;
#pragma unroll
  for (int i = 0; i < 7; i++) {
    int c = lane + 64 * i;
    x[i] = (c < CDIM) ? (double)row[c] : 0.0;
    s1 += x[i];
  }
  s1 = wredsumd(s1);
  double mu = s1 * (1.0 / (double)CDIM);
  double s2 = 0.0;
#pragma unroll
  for (int i = 0; i < 7; i++) {
    int c = lane + 64 * i;
    double d = (c < CDIM) ? (x[i] - mu) : 0.0;
    s2 += d * d;
  }
  s2 = wredsumd(s2);
  double rstd = 1.0 / sqrt(s2 * (1.0 / (double)CDIM) + 1e-5);
  double s3 = 0.0;
#pragma unroll
  for (int i = 0; i < 7; i++) {
    int c = lane + 64 * i;
    if (c < CDIM) {
      double y = (x[i] - mu) * rstd * (double)g[c] + (double)b[c];
      yc[i] = y;
      s3 += y * y;
    } else {
      yc[i] = 0.0;
    }
  }
  s3 = wredsumd(s3);
  double linv = 1.0 / fmax(sqrt(s3), 1e-12);
#pragma unroll
  for (int i = 0; i < 7; i++) yc[i] *= linv;
}

// ---------------- GEMM: logits[n][j] (fp32, output 1) ----------------
__global__ __launch_bounds__(256) void k_gemm(const float* __restrict__ feat,
                                              const float4* __restrict__ stats,
                                              const float* __restrict__ g,
                                              const float* __restrict__ b,
                                              const float* __restrict__ pT,
                                              float* __restrict__ logits) {
  __shared__ __align__(16) float As[128 * 20];
  __shared__ __align__(16) float Bs[JPAD * 20];
  int tid = threadIdx.x;
  int tx = tid & 15, ty = tid >> 4;
  int n0 = blockIdx.x * 128;
  float acc[8][9];
#pragma unroll
  for (int i = 0; i < 8; i++)
#pragma unroll
    for (int s = 0; s < 9; s++) acc[i][s] = 0.f;

  for (int c0 = 0; c0 < CPAD; c0 += 16) {
#pragma unroll
    for (int it = 0; it < 8; it++) {
      int idx = tid + 256 * it;
      int c = idx & 15, r = idx >> 4;
      int cg = c0 + c;
      float v = 0.f;
      if (cg < CDIM) {
        float xx = feat[(size_t)(n0 + r) * CDIM + cg];
        float4 st = stats[n0 + r];
        v = ((xx - st.x) * st.y * g[cg] + b[cg]) * st.z;
      }
      As[r * 20 + c] = v;
    }
#pragma unroll
    for (int it = 0; it < 9; it++) {
      int idx = tid + 256 * it;
      int c = idx / JPAD;
      int jj = idx - c * JPAD;
      Bs[jj * 20 + c] = pT[(size_t)(c0 + c) * JPAD + jj];
    }
    __syncthreads();
#pragma unroll
    for (int c = 0; c < 16; c += 4) {
      float4 av[8], bv[9];
#pragma unroll
      for (int i = 0; i < 8; i++) av[i] = *(const float4*)&As[(ty + 16 * i) * 20 + c];
#pragma unroll
      for (int s = 0; s < 9; s++) bv[s] = *(const float4*)&Bs[(tx + 16 * s) * 20 + c];
#pragma unroll
      for (int i = 0; i < 8; i++)
#pragma unroll
        for (int s = 0; s < 9; s++) {
          acc[i][s] += av[i].x * bv[s].x + av[i].y * bv[s].y +
                       av[i].z * bv[s].z + av[i].w * bv[s].w;
        }
    }
    __syncthreads();
  }
#pragma unroll
  for (int i = 0; i < 8; i++) {
    int n = n0 + ty + 16 * i;
#pragma unroll
    for (int s = 0; s < 9; s++) {
      int j = tx + 16 * s;
      if (j < KM) logits[(size_t)n * KM + j] = acc[i][s];
    }
  }
}

// ---------------- out_seg + correct bitmask (fp32, output 0) ----------------
__global__ __launch_bounds__(256) void k_seg(const float* __restrict__ logits,
                                             const float* __restrict__ mg,
                                             const float* __restrict__ mb,
                                             const int* __restrict__ gt,
                                             float* __restrict__ out_seg,
                                             unsigned* __restrict__ corrbits) {
  __shared__ float buf[4][KM];
  int wave = threadIdx.x >> 6, lane = threadIdx.x & 63;
  int n = blockIdx.x * 4 + wave;
  const float* row = logits + (size_t)n * KM;
  for (int j = lane; j < KM; j += 64) buf[wave][j] = row[j];
  __syncthreads();
  bool act = lane < KCLS;
  float v = -1e30f;
  if (act) {
    v = buf[wave][lane * MPROTO];
#pragma unroll
    for (int m = 1; m < MPROTO; m++) v = fmaxf(v, buf[wave][lane * MPROTO + m]);
  }
  float s = act ? v : 0.f;
#pragma unroll
  for (int off = 1; off < 16; off <<= 1) s += __shfl_xor(s, off, 16);
  float mu = s / (float)KCLS;
  float d = act ? (v - mu) : 0.f;
  float s2 = d * d;
#pragma unroll
  for (int off = 1; off < 16; off <<= 1) s2 += __shfl_xor(s2, off, 16);
  float rstd = rsqrtf(s2 / (float)KCLS + 1e-5f);
  float gk = act ? mg[lane] : 0.f;
  float bk = act ? mb[lane] : 0.f;
  float o = (v - mu) * rstd * gk + bk;
  if (act) out_seg[(size_t)n * KCLS + lane] = o;
  float bo = act ? o : -1e30f;
  int bi = act ? lane : (1 << 30);
#pragma unroll
  for (int off = 1; off < 16; off <<= 1) {
    float oo = __shfl_xor(bo, off, 16);
    int oi = __shfl_xor(bi, off, 16);
    if (oo > bo || (oo == bo && oi < bi)) { bo = oo; bi = oi; }
  }
  if (lane == 0 && bi == gt[n]) atomicOr(&corrbits[n >> 5], 1u << (n & 31));
}

// ---------------- pass A: fp64 dots -> fp32 scores into logits class slots; fp64 S ----
__global__ __launch_bounds__(256) void k_passA(const float* __restrict__ feat,
                                               const float* __restrict__ g,
                                               const float* __restrict__ b,
                                               const double* __restrict__ pnd,
                                               const int* __restrict__ gt,
                                               float* __restrict__ logits,
                                               double* __restrict__ Sd) {
  __shared__ double sSd[KCLS];
  int tid = threadIdx.x;
  if (tid < KCLS) sSd[tid] = 0.0;
  __syncthreads();
  int wave = tid >> 6, lane = tid & 63;
  int n = blockIdx.x * 4 + wave;
  int k = gt[n];
  double yc[7];
  row64(feat, n, g, b, yc);
  const double* pb = pnd + (size_t)k * MPROTO * CDIM;
  double dd[MPROTO];
#pragma unroll
  for (int m = 0; m < MPROTO; m++) {
    double d = 0.0;
#pragma unroll
    for (int i = 0; i < 7; i++) {
      int c = lane + 64 * i;
      if (c < CDIM) d += yc[i] * pb[(size_t)m * CDIM + c];
    }
    dd[m] = wredsumd(d);
  }
  if (lane == 0) {
    double se = 0.0;
    float* lp = logits + (size_t)n * KM + k * MPROTO;
#pragma unroll
    for (int m = 0; m < MPROTO; m++) {
      float s32 = (float)dd[m];
      lp[m] = s32;
      se += (double)expf(s32 / 0.05f);
    }
    atomicAdd(&sSd[k], se);
  }
  __syncthreads();
  if (tid < KCLS && sSd[tid] != 0.0) atomicAdd(&Sd[tid], sSd[tid]);
}

__global__ void k_sfin(const double* __restrict__ Sd, float* __restrict__ S32) {
  int k = threadIdx.x;
  if (k < KCLS) S32[k] = (float)Sd[k];
}

// ---------------- stable class-sorted pixel list ----------------
__global__ __launch_bounds__(256) void k_blkcnt(const int* __restrict__ gt,
                                                int* __restrict__ blkcnt) {
  __shared__ int c[KCLS];
  if (threadIdx.x < KCLS) c[threadIdx.x] = 0;
  __syncthreads();
  atomicAdd(&c[gt[blockIdx.x * 256 + threadIdx.x]], 1);
  __syncthreads();
  if (threadIdx.x < KCLS) blkcnt[blockIdx.x * KCLS + threadIdx.x] = c[threadIdx.x];
}

__global__ void k_scan(const int* __restrict__ blkcnt, int* __restrict__ blkoff,
                       int* __restrict__ classoff, int* __restrict__ cntI) {
  __shared__ int tot[KCLS], cbase[KCLS];
  int k = threadIdx.x;
  if (k < KCLS) {
    int t = 0;
    for (int bb = 0; bb < NBLK; bb++) t += blkcnt[bb * KCLS + k];
    tot[k] = t;
  }
  __syncthreads();
  if (k == 0) {
    int run = 0;
    for (int kk = 0; kk < KCLS; kk++) { cbase[kk] = run; run += tot[kk]; }
  }
  __syncthreads();
  if (k < KCLS) {
    cntI[k] = tot[k];
    classoff[k] = cbase[k];
    int run = cbase[k];
    for (int bb = 0; bb < NBLK; bb++) {
      blkoff[bb * KCLS + k] = run;
      run += blkcnt[bb * KCLS + k];
    }
  }
}

__global__ void k_scatter(const int* __restrict__ gt, const int* __restrict__ blkoff,
                          int* __restrict__ list) {
  __shared__ int soff[KCLS];
  if (threadIdx.x < KCLS) soff[threadIdx.x] = blkoff[blockIdx.x * KCLS + threadIdx.x];
  __syncthreads();
  if (threadIdx.x == 0) {
    int base = blockIdx.x * 256;
    for (int i = 0; i < 256; i++) {
      int k = gt[base + i];
      list[soff[k]++] = base + i;
    }
  }
}

// ---------------- numpy-order sequential column sums (one class per block) ----------
// stage 1: c1 = colsum(e/S);  stage 2: c2 = colsum(L after iter1);  stage 3: c3 after iter2
__global__ __launch_bounds__(64) void k_chain(const float* __restrict__ logits,
                                              const int* __restrict__ list,
                                              const int* __restrict__ classoff,
                                              const int* __restrict__ cntI,
                                              const float* __restrict__ S32,
                                              const float* __restrict__ c1,
                                              const float* __restrict__ c2,
                                              float* __restrict__ cout, int stage) {
  int k = blockIdx.x;
  int lane = threadIdx.x;
  bool act = lane < MPROTO;
  int coff = classoff[k];
  int cnt = cntI[k];
  float Sk = fmaxf(S32[k], 1e-12f);
  float Bf = fmaxf((float)cnt, 1.f);
  float d1 = 1.f, d2 = 1.f;
  if (act && stage >= 2) d1 = fmaxf(c1[k * MPROTO + lane], 1e-12f) * 10.f;
  if (act && stage >= 3) d2 = fmaxf(c2[k * MPROTO + lane], 1e-12f) * 10.f;
  float acc = 0.f;
  for (int i0 = 0; i0 < cnt; i0 += 8) {
    int nb = min(8, cnt - i0);
    float sv[8];
#pragma unroll
    for (int j = 0; j < 8; j++) {
      int n = list[coff + i0 + (j < nb ? j : 0)];
      sv[j] = act ? logits[(size_t)n * KM + k * MPROTO + lane] : 0.f;
    }
    float Lv[8];
#pragma unroll
    for (int j = 0; j < 8; j++) {
      float e = expf(sv[j] / 0.05f);
      float L = e / Sk;                                   // global norm (fp32 div)
      if (stage >= 2) {
        L = L / d1;                                       // iter1 col norm
        float r1 = nprow_lane(L);
        L = L / (fmaxf(r1, 1e-12f) * Bf);                 // iter1 row norm
        if (stage >= 3) {
          L = L / d2;                                     // iter2 col norm
          float r2 = nprow_lane(L);
          L = L / (fmaxf(r2, 1e-12f) * Bf);               // iter2 row norm
        }
      }
      Lv[j] = L;
    }
#pragma unroll
    for (int j = 0; j < 8; j++)
      if (j < nb) acc += Lv[j];                           // ordered fp32 accumulation
  }
  if (act) cout[k * MPROTO + lane] = acc;
}

// ---------------- final: full fp32 L chain + argmax (first-index ties) --------------
__global__ __launch_bounds__(256) void k_final(const float* __restrict__ logits,
                                               const int* __restrict__ gt,
                                               const float* __restrict__ c1,
                                               const float* __restrict__ c2,
                                               const float* __restrict__ c3,
                                               const float* __restrict__ S32,
                                               const int* __restrict__ cntI,
                                               const unsigned* __restrict__ corrbits,
                                               float* __restrict__ ptarget,
                                               int* __restrict__ acc_a) {
  int n = blockIdx.x * 256 + threadIdx.x;
  int k = gt[n];
  const float* sp = logits + (size_t)n * KM + k * MPROTO;
  float Bc = (float)cntI[k];
  float Bf = fmaxf(Bc, 1.f);
  float Sk = fmaxf(S32[k], 1e-12f);
  float L[MPROTO];
#pragma unroll
  for (int m = 0; m < MPROTO; m++) {
    float e = expf(sp[m] / 0.05f);
    float Lg = e / Sk;
    float d1 = fmaxf(c1[k * MPROTO + m], 1e-12f) * 10.f;
    L[m] = Lg / d1;
  }
  float r1 = nprow10(L);
  float den1 = fmaxf(r1, 1e-12f) * Bf;
#pragma unroll
  for (int m = 0; m < MPROTO; m++) L[m] = L[m] / den1;
#pragma unroll
  for (int m = 0; m < MPROTO; m++) {
    float d2 = fmaxf(c2[k * MPROTO + m], 1e-12f) * 10.f;
    L[m] = L[m] / d2;
  }
  float r2 = nprow10(L);
  float den2 = fmaxf(r2, 1e-12f) * Bf;
#pragma unroll
  for (int m = 0; m < MPROTO; m++) L[m] = L[m] / den2;
#pragma unroll
  for (int m = 0; m < MPROTO; m++) {
    float d3 = fmaxf(c3[k * MPROTO + m], 1e-12f) * 10.f;
    L[m] = L[m] / d3;
  }
  float r3 = nprow10(L);
  float den3 = fmaxf(r3, 1e-12f) * Bf;
#pragma unroll
  for (int m = 0; m < MPROTO; m++) L[m] = (L[m] / den3) * Bc;
  float best = L[0];
  int bi = 0;
#pragma unroll
  for (int m = 1; m < MPROTO; m++)
    if (L[m] > best) { best = L[m]; bi = m; }             // strict >, first-index ties
  ptarget[n] = (float)(bi + MPROTO * k);
  int corr = (corrbits[n >> 5] >> (n & 31)) & 1;
  acc_a[n] = corr ? (k * MPROTO + bi) : -1;
}

// ---------------- f accumulation (fp32) ----------------
__global__ __launch_bounds__(256) void k_faccum(const float* __restrict__ feat,
                                                const float4* __restrict__ stats,
                                                const float* __restrict__ g,
                                                const float* __restrict__ b,
                                                const int* __restrict__ acc_a,
                                                float* __restrict__ f,
                                                float* __restrict__ cnt) {
  __shared__ float accf[KM * 33];
  __shared__ int al[256];
  __shared__ float cl[KM];
  int tid = threadIdx.x;
  int tc = tid & 31, tp = tid >> 5;
  int c0 = blockIdx.y * 32;
  int w = min(32, CDIM - c0);
  for (int i = tid; i < KM * 33; i += 256) accf[i] = 0.f;
  if (blockIdx.y == 0)
    for (int i = tid; i < KM; i += 256) cl[i] = 0.f;
  __syncthreads();
  float gg = 0.f, bb = 0.f;
  if (tc < w) { gg = g[c0 + tc]; bb = b[c0 + tc]; }
  int base0 = blockIdx.x * (NPIX / 32);
  for (int sup = 0; sup < NPIX / 32; sup += 256) {
    int pbase = base0 + sup;
    al[tid] = acc_a[pbase + tid];
    __syncthreads();
    for (int sub = 0; sub < 256; sub += 8) {
      int a = al[sub + tp];
      if (a >= 0) {
        int p = pbase + sub + tp;
        if (tc < w) {
          float4 st = stats[p];
          float xx = feat[(size_t)p * CDIM + c0 + tc];
          float y = ((xx - st.x) * st.y * gg + bb) * st.z;
          atomicAdd(&accf[a * 33 + tc], y);
        }
        if (blockIdx.y == 0 && tc == 0) atomicAdd(&cl[a], 1.f);
      }
    }
    __syncthreads();
  }
  for (int j = tp; j < KM; j += 8)
    if (tc < w) atomicAdd(&f[(size_t)j * CDIM + c0 + tc], accf[j * 33 + tc]);
  if (blockIdx.y == 0)
    for (int i = tid; i < KM; i += 256) atomicAdd(&cnt[i], cl[i]);
}

// ---------------- momentum update + final l2norm (fp32, output 3) ----------------
__global__ void k_momentum(const double* __restrict__ pnd, const float* __restrict__ f,
                           const float* __restrict__ cnt, float* __restrict__ outp) {
  int j = blockIdx.x;
  int lane = threadIdx.x;
  float fv[7];
  float ss = 0.f;
#pragma unroll
  for (int i = 0; i < 7; i++) {
    int c = lane + 64 * i;
    fv[i] = (c < CDIM) ? f[(size_t)j * CDIM + c] : 0.f;
    ss += fv[i] * fv[i];
  }
  ss = wredsum(ss);
  float rinv = 1.f / fmaxf(sqrtf(ss), 1e-12f);
  bool doupd = cnt[j] > 0.f;
  float sel[7];
  float s2 = 0.f;
#pragma unroll
  for (int i = 0; i < 7; i++) {
    int c = lane + 64 * i;
    float pv = (c < CDIM) ? (float)pnd[(size_t)j * CDIM + c] : 0.f;
    float u = 0.999f * pv + 0.001f * (fv[i] * rinv);
    sel[i] = doupd ? u : pv;
    s2 += sel[i] * sel[i];
  }
  s2 = wredsum(s2);
  float r2 = 1.f / fmaxf(sqrtf(s2), 1e-12f);
#pragma unroll
  for (int i = 0; i < 7; i++) {
    int c = lane + 64 * i;
    if (c < CDIM) outp[(size_t)j * CDIM + c] = sel[i] * r2;
  }
}

extern "C" void kernel_launch(void* const* d_in, const int* in_sizes, int n_in,
                              void* d_out, int out_size, void* d_ws, size_t ws_size,
                              hipStream_t stream) {
  const float* feat = (const float*)d_in[0];
  const float* protos = (const float*)d_in[1];
  const float* fg = (const float*)d_in[2];
  const float* fb = (const float*)d_in[3];
  const float* mg = (const float*)d_in[4];
  const float* mb = (const float*)d_in[5];
  const int* gt = (const int*)d_in[6];

  float* out = (float*)d_out;
  float* out_seg = out;                              // [N, K]
  float* logits = out + (size_t)NPIX * KCLS;         // [N, KM]
  float* ptarget = logits + (size_t)NPIX * KM;       // [N]
  float* newp = ptarget + NPIX;                      // [KM, C]

  float* ws = (float*)d_ws;
  float* c1 = ws + OFF_C1;
  float* c2 = ws + OFF_C2;
  float* c3 = ws + OFF_C3;
  float* S32 = ws + OFF_S32;
  double* Sd = (double*)(ws + OFF_SD);
  int* cntI = (int*)(ws + OFF_CNTI);
  int* classoff = (int*)(ws + OFF_COFF);
  float* cnt = ws + OFF_CNT;
  float* fbuf = ws + OFF_F;
  unsigned* corrbits = (unsigned*)(ws + OFF_CBITS);
  int* blkcnt = (int*)(ws + OFF_BLKC);
  int* blkoff = (int*)(ws + OFF_BLKO);
  float* pT = ws + OFF_PT;
  double* pnd = (double*)(ws + OFF_PND);
  float4* stats = (float4*)(ws + OFF_STATS);
  int* list = (int*)(ws + OFF_LIST);
  int* acc_a = (int*)(ws + OFF_ACCA);

  k_zero<<<(ZERO_N + 255) / 256, 256, 0, stream>>>(ws);
  k_protonorm<<<JPAD, 64, 0, stream>>>(protos, pT, pnd);
  k_rowstats<<<NPIX / 4, 256, 0, stream>>>(feat, fg, fb, stats);
  k_gemm<<<NPIX / 128, 256, 0, stream>>>(feat, stats, fg, fb, pT, logits);
  k_seg<<<NPIX / 4, 256, 0, stream>>>(logits, mg, mb, gt, out_seg, corrbits);
  k_passA<<<NPIX / 4, 256, 0, stream>>>(feat, fg, fb, pnd, gt, logits, Sd);
  k_blkcnt<<<NBLK, 256, 0, stream>>>(gt, blkcnt);
  k_scan<<<1, 64, 0, stream>>>(blkcnt, blkoff, classoff, cntI);
  k_scatter<<<NBLK, 64, 0, stream>>>(gt, blkoff, list);
  k_sfin<<<1, 64, 0, stream>>>(Sd, S32);
  k_chain<<<KCLS, 64, 0, stream>>>(logits, list, classoff, cntI, S32, c1, c2, c1, 1);
  k_chain<<<KCLS, 64, 0, stream>>>(logits, list, classoff, cntI, S32, c1, c2, c2, 2);
  k_chain<<<KCLS, 64, 0, stream>>>(logits, list, classoff, cntI, S32, c1, c2, c3, 3);
  k_final<<<NBLK, 256, 0, stream>>>(logits, gt, c1, c2, c3, S32, cntI, corrbits,
                                    ptarget, acc_a);
  k_faccum<<<dim3(32, 14), 256, 0, stream>>>(feat, stats, fg, fb, acc_a, fbuf, cnt);
  k_momentum<<<KM, 64, 0, stream>>>(pnd, fbuf, cnt, newp);
}